// Round 9
// baseline (255.871 us; speedup 1.0000x reference)
//
#include <hip/hip_runtime.h>
#include <hip/hip_bf16.h>

#define NB 8
#define BIN 512
#define BOUT 512
#define BATCH 8192
#define DIM 4096   // NB*BIN

typedef __attribute__((ext_vector_type(8))) short bf16x8;
typedef __attribute__((ext_vector_type(4))) float f32x4;

#define SWZ16(r) (((r) & 15) << 4)

__device__ __forceinline__ unsigned short f2bf(float f) {
    return __builtin_bit_cast(unsigned short, __float2bfloat16(f));
}

__device__ __forceinline__ unsigned long long pack4(f32x4 f) {
    return (unsigned long long)f2bf(f.x)
         | ((unsigned long long)f2bf(f.y) << 16)
         | ((unsigned long long)f2bf(f.z) << 32)
         | ((unsigned long long)f2bf(f.w) << 48);
}

// ---------------- weight pack: f32 [nb][512][512] -> per-(nb,wn) bf16 fragment streams ----------------
// Stream layout: frag (nb, wn 0..3, kidx 0..15, n 0..7): 64 lanes x 16B, contiguous 1KB.
__global__ void pack_w(const float* __restrict__ W, unsigned short* __restrict__ pk) {
    int gid = blockIdx.x * 256 + threadIdx.x;        // 262144 total
    int lane = gid & 63;
    int n    = (gid >> 6) & 7;
    int kidx = (gid >> 9) & 15;
    int wn   = (gid >> 13) & 3;
    int nb   = gid >> 15;
    int row  = wn * 128 + n * 16 + (lane & 15);      // 0..511 within block
    int col  = kidx * 32 + (lane >> 4) * 8;          // 0..511
    const float* s = W + ((size_t)nb * BOUT + row) * BIN + col;
    f32x4 a = *(const f32x4*)s;
    f32x4 b = *(const f32x4*)(s + 4);
    unsigned long long* d = (unsigned long long*)(pk + (size_t)gid * 8);
    d[0] = pack4(a);
    d[1] = pack4(b);
}

// ---------------- fused 2-layer block-diag MLP ----------------
// wg: 64 batch rows x one full diagonal block (512 cols), both layers.
// 256 threads = 4 waves (1x4 over cols); per wave 64x128 out = 4x8 f32x4 acc.
// Full x-tile (64x512 bf16 = 64 KB) staged once (SWZ16, conflict-free); both
// phases are barrier-free halfstep streams. W fragments are per-wave private
// register streams with a 4-deep round-robin buffer (q0..q3): the load for
// halfstep k+3 issues at step k (~3 halfsteps == ~1800 cy of lead, covering
// L3-class latency). Compiler emits exact vmcnt(24) per step via reg deps.
__global__ __launch_bounds__(256, 2)
void fused_mlp(const float* __restrict__ X,
               const unsigned short* __restrict__ PK1,
               const float* __restrict__ B1,
               const unsigned short* __restrict__ PK2,
               const float* __restrict__ B2,
               float* __restrict__ Out)
{
    __shared__ __align__(16) unsigned char XH[65536];   // [64 rows][1024B], SWZ16; x then h

    const int bid = blockIdx.x;
    const int nb = bid & 7;       // XCD-pin heuristic (harmless if mapping differs)
    const int mt = bid >> 3;      // 0..127

    const int t = threadIdx.x;
    const int lane = t & 63;
    const int wn = t >> 6;        // 0..3
    const int l15 = lane & 15;
    const int lhi = lane >> 4;

    const int row0 = mt * 64;
    const int wc0  = nb * 512;

    // A-read bases: r = m*16+l15; addr(m,kk) = ab[m][kk&3] + (kk>>2)*256
    int ab[4][4];
    #pragma unroll
    for (int m = 0; m < 4; m++) {
        const int r_ = m * 16 + l15;
        #pragma unroll
        for (int p = 0; p < 4; p++)
            ab[m][p] = r_ * 1024 + ((p * 64 + lhi * 16) ^ SWZ16(r_));
    }

    const unsigned short* wp1 = PK1 + (size_t)(nb * 4 + wn) * 65536 + lane * 8;
    const unsigned short* wp2 = PK2 + (size_t)(nb * 4 + wn) * 65536 + lane * 8;

    f32x4 acc[4][8];
    #pragma unroll
    for (int m = 0; m < 4; m++)
        #pragma unroll
        for (int n = 0; n < 8; n++)
            acc[m][n] = (f32x4)(0.f);

    bf16x8 q0[8], q1[8], q2[8], q3[8];

#define LOADQ(Q, WPTR) { \
    _Pragma("unroll") for (int n = 0; n < 8; n++) \
        Q[n] = *(const bf16x8*)((WPTR) + n * 512); \
    (WPTR) += 4096; }

#define MFMA32(Q, AF) \
    __builtin_amdgcn_s_setprio(1); \
    _Pragma("unroll") for (int m = 0; m < 4; m++) \
        _Pragma("unroll") for (int n = 0; n < 8; n++) \
            acc[m][n] = __builtin_amdgcn_mfma_f32_16x16x32_bf16(AF[m], Q[n], acc[m][n], 0, 0, 0); \
    __builtin_amdgcn_s_setprio(0);

// halfstep K: issue W loads for halfstep K+3 into QN, ds_read af, 32 MFMA on QC
#define HSTEP(K, QC, QN, WPTR) { \
    LOADQ(QN, WPTR); \
    bf16x8 af[4]; \
    _Pragma("unroll") for (int m = 0; m < 4; m++) \
        af[m] = *(const bf16x8*)(XH + ab[m][(K) & 3] + ((K) >> 2) * 256); \
    MFMA32(QC, af) }

#define HSTEP_NL(K, QC) { \
    bf16x8 af[4]; \
    _Pragma("unroll") for (int m = 0; m < 4; m++) \
        af[m] = *(const bf16x8*)(XH + ab[m][(K) & 3] + ((K) >> 2) * 256); \
    MFMA32(QC, af) }

#define BAR() { \
    asm volatile("s_waitcnt lgkmcnt(0)" ::: "memory"); \
    __builtin_amdgcn_s_barrier(); \
    __builtin_amdgcn_sched_barrier(0); }

    // ---- prologue: 3-deep W1 prefetch (kidx 0,1,2) flies during x staging ----
    LOADQ(q0, wp1);
    LOADQ(q1, wp1);
    LOADQ(q2, wp1);

    // ---- stage FULL x tile: [64 rows][512 f32] -> bf16, SWZ16-swizzled into XH ----
    {
        const int sr = t >> 2;                       // row 0..63
        const int cb = (t & 3) * 256;                // byte base within row (256B per thread)
        const float* xr = X + (size_t)(row0 + sr) * DIM + wc0 + (t & 3) * 128;
        #pragma unroll
        for (int i = 0; i < 8; i++) {
            f32x4 a = *(const f32x4*)(xr + i * 16 + 0);
            f32x4 b = *(const f32x4*)(xr + i * 16 + 4);
            f32x4 c = *(const f32x4*)(xr + i * 16 + 8);
            f32x4 d = *(const f32x4*)(xr + i * 16 + 12);
            bf16x8 v0, v1;
            ((unsigned long long*)&v0)[0] = pack4(a);
            ((unsigned long long*)&v0)[1] = pack4(b);
            ((unsigned long long*)&v1)[0] = pack4(c);
            ((unsigned long long*)&v1)[1] = pack4(d);
            *(bf16x8*)(XH + sr * 1024 + (((cb + i * 32)     ) ^ SWZ16(sr))) = v0;
            *(bf16x8*)(XH + sr * 1024 + (((cb + i * 32) + 16) ^ SWZ16(sr))) = v1;
        }
    }
    BAR();

    // ================= phase 1: acc = x @ W1^T (barrier-free) =================
    HSTEP(0,  q0, q3, wp1)  HSTEP(1,  q1, q0, wp1)  HSTEP(2,  q2, q1, wp1)  HSTEP(3,  q3, q2, wp1)
    HSTEP(4,  q0, q3, wp1)  HSTEP(5,  q1, q0, wp1)  HSTEP(6,  q2, q1, wp1)  HSTEP(7,  q3, q2, wp1)
    HSTEP(8,  q0, q3, wp1)  HSTEP(9,  q1, q0, wp1)  HSTEP(10, q2, q1, wp1)  HSTEP(11, q3, q2, wp1)
    HSTEP(12, q0, q3, wp1)  HSTEP(13, q1, q0, wp2)  HSTEP(14, q2, q1, wp2)  HSTEP(15, q3, q2, wp2)

    BAR();   // all XH(x) ds_reads retired in every wave -> safe to overwrite with h

    // ---- h = relu(acc + b1) -> XH (same SWZ16 layout) ----
    #pragma unroll
    for (int n = 0; n < 8; n++) {
        const int c = wn * 128 + n * 16 + l15;
        const float bv = B1[wc0 + c];
        #pragma unroll
        for (int m = 0; m < 4; m++) {
            #pragma unroll
            for (int rr = 0; rr < 4; rr++) {
                float v = acc[m][n][rr] + bv;
                v = v > 0.f ? v : 0.f;
                const int r = m * 16 + lhi * 4 + rr;
                *(unsigned short*)(XH + r * 1024 + ((c * 2) ^ SWZ16(r))) = f2bf(v);
            }
        }
    }
    BAR();   // h visible to all waves

    #pragma unroll
    for (int m = 0; m < 4; m++)
        #pragma unroll
        for (int n = 0; n < 8; n++)
            acc[m][n] = (f32x4)(0.f);

    // ================= phase 2: acc = h @ W2^T (barrier-free) =================
    HSTEP(0,  q0, q3, wp2)  HSTEP(1,  q1, q0, wp2)  HSTEP(2,  q2, q1, wp2)  HSTEP(3,  q3, q2, wp2)
    HSTEP(4,  q0, q3, wp2)  HSTEP(5,  q1, q0, wp2)  HSTEP(6,  q2, q1, wp2)  HSTEP(7,  q3, q2, wp2)
    HSTEP(8,  q0, q3, wp2)  HSTEP(9,  q1, q0, wp2)  HSTEP(10, q2, q1, wp2)  HSTEP(11, q3, q2, wp2)
    HSTEP(12, q0, q3, wp2)  HSTEP_NL(13, q1)        HSTEP_NL(14, q2)        HSTEP_NL(15, q3)

    // ---- epilogue: out = relu(acc + b2), f32 ----
    #pragma unroll
    for (int n = 0; n < 8; n++) {
        const int c = wc0 + wn * 128 + n * 16 + l15;
        const float bv = B2[c];
        #pragma unroll
        for (int m = 0; m < 4; m++) {
            const int rb = row0 + m * 16 + lhi * 4;
            #pragma unroll
            for (int rr = 0; rr < 4; rr++) {
                float v = acc[m][n][rr] + bv;
                Out[(size_t)(rb + rr) * DIM + c] = v > 0.f ? v : 0.f;
            }
        }
    }

#undef LOADQ
#undef MFMA32
#undef HSTEP
#undef HSTEP_NL
#undef BAR
}

extern "C" void kernel_launch(void* const* d_in, const int* in_sizes, int n_in,
                              void* d_out, int out_size, void* d_ws, size_t ws_size,
                              hipStream_t stream) {
    const float* x  = (const float*)d_in[0];
    const float* W1 = (const float*)d_in[1];
    const float* b1 = (const float*)d_in[2];
    const float* W2 = (const float*)d_in[3];
    const float* b2 = (const float*)d_in[4];
    float* out = (float*)d_out;

    char* ws = (char*)d_ws;
    unsigned short* PK1 = (unsigned short*)ws;                 // 4 MB
    unsigned short* PK2 = (unsigned short*)(ws + (4u << 20));  // 4 MB

    pack_w<<<1024, 256, 0, stream>>>(W1, PK1);
    pack_w<<<1024, 256, 0, stream>>>(W2, PK2);

    const int GRID = NB * (BATCH / 64);     // 1024
    fused_mlp<<<GRID, 256, 0, stream>>>(x, PK1, b1, PK2, b2, out);
}

// Round 11
// 97.893 us; speedup vs baseline: 2.6138x; 2.6138x over previous
//
#include <hip/hip_runtime.h>
#include <hip/hip_bf16.h>

#define NB 8
#define BIN 512
#define BOUT 512
#define BATCH 8192
#define DIM 4096   // NB*BIN

typedef __attribute__((ext_vector_type(8))) short bf16x8;
typedef __attribute__((ext_vector_type(4))) float f32x4;

#define SWZ8(r) (((r) & 7) << 4)

__device__ __forceinline__ unsigned short f2bf(float f) {
    return __builtin_bit_cast(unsigned short, __float2bfloat16(f));
}

__device__ __forceinline__ unsigned long long pack4(f32x4 f) {
    return (unsigned long long)f2bf(f.x)
         | ((unsigned long long)f2bf(f.y) << 16)
         | ((unsigned long long)f2bf(f.z) << 32)
         | ((unsigned long long)f2bf(f.w) << 48);
}

// ---------------- weight pack ----------------
// Layout: (nb, wid 0..7, kidx 0..15, nf 0..3, lane 0..63) x 8 ushorts.
// Fragment: lane -> row = wid*64 + nf*16 + (lane&15), col = kidx*32 + (lane>>4)*8.
// Per (nb,wid): 32768 ush (64 KB), advancing 2048 ush per kidx.
__global__ void pack_w(const float* __restrict__ W, unsigned short* __restrict__ pk) {
    int gid = blockIdx.x * 256 + threadIdx.x;        // 262144 total
    int lane = gid & 63;
    int nf   = (gid >> 6) & 3;
    int kidx = (gid >> 8) & 15;
    int wid  = (gid >> 12) & 7;
    int nb   = gid >> 15;
    int row  = wid * 64 + nf * 16 + (lane & 15);     // 0..511 within block
    int col  = kidx * 32 + (lane >> 4) * 8;          // 0..511
    const float* s = W + ((size_t)nb * BOUT + row) * BIN + col;
    f32x4 a = *(const f32x4*)s;
    f32x4 b = *(const f32x4*)(s + 4);
    unsigned long long* d = (unsigned long long*)(pk + (size_t)gid * 8);
    d[0] = pack4(a);
    d[1] = pack4(b);
}

// ---------------- fused 2-layer block-diag MLP ----------------
// wg: 64 batch rows x one full diagonal block (512 cols). 512 threads = 8 waves;
// wave wid owns cols wid*64..+64. acc = 4x4 f32x4 = 64 AGPR -> with q 2-deep
// (32 VGPR) total fits 128 regs => 4 waves/SIMD, 2 wgs/CU (16 waves/CU).
// x tile (64x512 bf16, SWZ8) staged once; both phases are barrier-free
// halfstep streams; sched_barrier(0) after each LOADQ pins load-issue order
// so the 1-halfstep register prefetch lead is real. Bias via LDS.
// W-stream ledger: wp1 advances 16x (prologue + HSTEP 0..14 of phase 1);
// wp2 advances 16x (phase-1 HSTEP(15) seeds W2k0, phase-2 HSTEP 0..14).
__global__ __launch_bounds__(512, 4)
void fused_mlp(const float* __restrict__ X,
               const unsigned short* __restrict__ PK1,
               const float* __restrict__ B1,
               const unsigned short* __restrict__ PK2,
               const float* __restrict__ B2,
               float* __restrict__ Out)
{
    __shared__ __align__(16) unsigned char XH[65536];   // [64 rows][1024B], SWZ8; x then h
    __shared__ __align__(16) float BS[1024];            // bias: [0..511]=b1, [512..1023]=b2

    const int bid = blockIdx.x;
    const int nb = bid & 7;       // XCD-pin heuristic
    const int mt = bid >> 3;      // 0..127

    const int t = threadIdx.x;
    const int lane = t & 63;
    const int wid = t >> 6;       // 0..7 -> col slice wid*64
    const int l15 = lane & 15;
    const int lhi = lane >> 4;

    const int row0 = mt * 64;
    const int wc0  = nb * 512;

    // A-read bases: r = m*16+l15; addr(m,kk) = ab[m][kk&1] + (kk>>1)*128
    // (SWZ8 touches bits 4-6; (kk&1)*64 folded into base, (kk>>1)*128 additive)
    int ab[4][2];
    #pragma unroll
    for (int m = 0; m < 4; m++) {
        const int r_ = m * 16 + l15;
        #pragma unroll
        for (int p = 0; p < 2; p++)
            ab[m][p] = r_ * 1024 + ((p * 64 + lhi * 16) ^ SWZ8(r_));
    }

    const unsigned short* wp1 = PK1 + (size_t)(nb * 8 + wid) * 32768 + lane * 8;
    const unsigned short* wp2 = PK2 + (size_t)(nb * 8 + wid) * 32768 + lane * 8;

    f32x4 acc[4][4];
    #pragma unroll
    for (int m = 0; m < 4; m++)
        #pragma unroll
        for (int n = 0; n < 4; n++)
            acc[m][n] = (f32x4)(0.f);

    bf16x8 q0[4], q1[4];

#define LOADQ(Q, WPTR) { \
    _Pragma("unroll") for (int n = 0; n < 4; n++) \
        Q[n] = *(const bf16x8*)((WPTR) + n * 512); \
    (WPTR) += 2048; \
    __builtin_amdgcn_sched_barrier(0); }

// halfstep K: issue W loads for K+1 into QN, then af ds_reads + 16 MFMA on QC
#define HSTEP(K, QC, QN, WPTR) { \
    LOADQ(QN, WPTR); \
    __builtin_amdgcn_s_setprio(1); \
    _Pragma("unroll") for (int m = 0; m < 4; m++) { \
        bf16x8 af = *(const bf16x8*)(XH + ab[m][(K) & 1] + ((K) >> 1) * 128); \
        _Pragma("unroll") for (int n = 0; n < 4; n++) \
            acc[m][n] = __builtin_amdgcn_mfma_f32_16x16x32_bf16(af, QC[n], acc[m][n], 0, 0, 0); \
    } \
    __builtin_amdgcn_s_setprio(0); }

#define HSTEP_NL(K, QC) { \
    __builtin_amdgcn_s_setprio(1); \
    _Pragma("unroll") for (int m = 0; m < 4; m++) { \
        bf16x8 af = *(const bf16x8*)(XH + ab[m][(K) & 1] + ((K) >> 1) * 128); \
        _Pragma("unroll") for (int n = 0; n < 4; n++) \
            acc[m][n] = __builtin_amdgcn_mfma_f32_16x16x32_bf16(af, QC[n], acc[m][n], 0, 0, 0); \
    } \
    __builtin_amdgcn_s_setprio(0); }

#define BAR() { \
    asm volatile("s_waitcnt lgkmcnt(0)" ::: "memory"); \
    __builtin_amdgcn_s_barrier(); \
    __builtin_amdgcn_sched_barrier(0); }

    // ---- prologue: W1 kidx0 prefetch + bias->LDS + full x tile -> XH ----
    LOADQ(q0, wp1);
    BS[t]       = B1[wc0 + t];
    BS[512 + t] = B2[wc0 + t];
    {
        // 512 threads stage [64 rows][512 f32] -> bf16, SWZ8-swizzled
        const int sr = t >> 3;                        // row 0..63
        const int cb = (t & 7) * 128;                 // byte base within row
        const float* xr = X + (size_t)(row0 + sr) * DIM + wc0 + (t & 7) * 64;
        #pragma unroll
        for (int i = 0; i < 8; i++) {
            f32x4 a = *(const f32x4*)(xr + i * 8);
            f32x4 b = *(const f32x4*)(xr + i * 8 + 4);
            bf16x8 v;
            ((unsigned long long*)&v)[0] = pack4(a);
            ((unsigned long long*)&v)[1] = pack4(b);
            *(bf16x8*)(XH + sr * 1024 + ((cb + i * 16) ^ SWZ8(sr))) = v;
        }
    }
    BAR();

    // ================= phase 1: acc = x @ W1^T (barrier-free) =================
    HSTEP(0,  q0, q1, wp1)  HSTEP(1,  q1, q0, wp1)  HSTEP(2,  q0, q1, wp1)  HSTEP(3,  q1, q0, wp1)
    HSTEP(4,  q0, q1, wp1)  HSTEP(5,  q1, q0, wp1)  HSTEP(6,  q0, q1, wp1)  HSTEP(7,  q1, q0, wp1)
    HSTEP(8,  q0, q1, wp1)  HSTEP(9,  q1, q0, wp1)  HSTEP(10, q0, q1, wp1)  HSTEP(11, q1, q0, wp1)
    HSTEP(12, q0, q1, wp1)  HSTEP(13, q1, q0, wp1)  HSTEP(14, q0, q1, wp1)  HSTEP(15, q1, q0, wp2)

    BAR();   // all XH(x) ds_reads retired in every wave -> safe to overwrite with h

    // ---- h = relu(acc + b1) -> XH (same SWZ8 layout); bias from LDS ----
    #pragma unroll
    for (int n = 0; n < 4; n++) {
        const int c = wid * 64 + n * 16 + l15;
        const float bv = BS[c];
        #pragma unroll
        for (int m = 0; m < 4; m++) {
            #pragma unroll
            for (int rr = 0; rr < 4; rr++) {
                float v = acc[m][n][rr] + bv;
                v = v > 0.f ? v : 0.f;
                const int r = m * 16 + lhi * 4 + rr;
                *(unsigned short*)(XH + r * 1024 + ((c * 2) ^ SWZ8(r))) = f2bf(v);
            }
        }
    }
    BAR();   // h visible to all waves

    #pragma unroll
    for (int m = 0; m < 4; m++)
        #pragma unroll
        for (int n = 0; n < 4; n++)
            acc[m][n] = (f32x4)(0.f);

    // ================= phase 2: acc = h @ W2^T (barrier-free) =================
    HSTEP(0,  q0, q1, wp2)  HSTEP(1,  q1, q0, wp2)  HSTEP(2,  q0, q1, wp2)  HSTEP(3,  q1, q0, wp2)
    HSTEP(4,  q0, q1, wp2)  HSTEP(5,  q1, q0, wp2)  HSTEP(6,  q0, q1, wp2)  HSTEP(7,  q1, q0, wp2)
    HSTEP(8,  q0, q1, wp2)  HSTEP(9,  q1, q0, wp2)  HSTEP(10, q0, q1, wp2)  HSTEP(11, q1, q0, wp2)
    HSTEP(12, q0, q1, wp2)  HSTEP(13, q1, q0, wp2)  HSTEP(14, q0, q1, wp2)  HSTEP_NL(15, q1)

    // ---- epilogue: out = relu(acc + b2), f32; bias from LDS ----
    #pragma unroll
    for (int n = 0; n < 4; n++) {
        const int cl = wid * 64 + n * 16 + l15;
        const float bv = BS[512 + cl];
        const int c = wc0 + cl;
        #pragma unroll
        for (int m = 0; m < 4; m++) {
            const int rb = row0 + m * 16 + lhi * 4;
            #pragma unroll
            for (int rr = 0; rr < 4; rr++) {
                float v = acc[m][n][rr] + bv;
                Out[(size_t)(rb + rr) * DIM + c] = v > 0.f ? v : 0.f;
            }
        }
    }

#undef LOADQ
#undef HSTEP
#undef HSTEP_NL
#undef BAR
}

extern "C" void kernel_launch(void* const* d_in, const int* in_sizes, int n_in,
                              void* d_out, int out_size, void* d_ws, size_t ws_size,
                              hipStream_t stream) {
    const float* x  = (const float*)d_in[0];
    const float* W1 = (const float*)d_in[1];
    const float* b1 = (const float*)d_in[2];
    const float* W2 = (const float*)d_in[3];
    const float* b2 = (const float*)d_in[4];
    float* out = (float*)d_out;

    char* ws = (char*)d_ws;
    unsigned short* PK1 = (unsigned short*)ws;                 // 4 MB
    unsigned short* PK2 = (unsigned short*)(ws + (4u << 20));  // 4 MB

    pack_w<<<1024, 256, 0, stream>>>(W1, PK1);
    pack_w<<<1024, 256, 0, stream>>>(W2, PK2);

    const int GRID = NB * (BATCH / 64);     // 1024
    fused_mlp<<<GRID, 512, 0, stream>>>(x, PK1, b1, PK2, b2, out);
}

// Round 12
// 96.298 us; speedup vs baseline: 2.6571x; 1.0166x over previous
//
#include <hip/hip_runtime.h>
#include <hip/hip_bf16.h>

#define NB 8
#define BIN 512
#define BOUT 512
#define BATCH 8192
#define DIM 4096   // NB*BIN

typedef __attribute__((ext_vector_type(8))) short bf16x8;
typedef __attribute__((ext_vector_type(4))) float f32x4;

#define SWZ8(r) (((r) & 7) << 4)

__device__ __forceinline__ unsigned short f2bf(float f) {
    return __builtin_bit_cast(unsigned short, __float2bfloat16(f));
}

__device__ __forceinline__ unsigned long long pack4(f32x4 f) {
    return (unsigned long long)f2bf(f.x)
         | ((unsigned long long)f2bf(f.y) << 16)
         | ((unsigned long long)f2bf(f.z) << 32)
         | ((unsigned long long)f2bf(f.w) << 48);
}

// ---------------- weight pack ----------------
// Layout: (nb, wid 0..7, kidx 0..15, nf 0..3, lane 0..63) x 8 ushorts.
// Fragment: lane -> row = wid*64 + nf*16 + (lane&15), col = kidx*32 + (lane>>4)*8.
// Per (nb,wid): 32768 ush (64 KB), advancing 2048 ush per kidx.
__global__ void pack_w(const float* __restrict__ W, unsigned short* __restrict__ pk) {
    int gid = blockIdx.x * 256 + threadIdx.x;        // 262144 total
    int lane = gid & 63;
    int nf   = (gid >> 6) & 3;
    int kidx = (gid >> 8) & 15;
    int wid  = (gid >> 12) & 7;
    int nb   = gid >> 15;
    int row  = wid * 64 + nf * 16 + (lane & 15);     // 0..511 within block
    int col  = kidx * 32 + (lane >> 4) * 8;          // 0..511
    const float* s = W + ((size_t)nb * BOUT + row) * BIN + col;
    f32x4 a = *(const f32x4*)s;
    f32x4 b = *(const f32x4*)(s + 4);
    unsigned long long* d = (unsigned long long*)(pk + (size_t)gid * 8);
    d[0] = pack4(a);
    d[1] = pack4(b);
}

// ---------------- fused 2-layer block-diag MLP ----------------
// wg: 128 batch rows x one full diagonal block (512 cols). 512 threads = 8 waves;
// wave wid owns cols wid*64..+64 over ALL 128 rows -> acc 8x4 f32x4 (128 AGPR).
// Doubling rows/wg halves the chip-wide W fragment traffic (1 GB -> 512 MB),
// the hypothesized Infinity-Cache-BW wall. x tile (128x512 bf16 = 128 KB, SWZ8)
// staged once; both phases barrier-free halfstep streams with 2-deep register
// W prefetch (sched_barrier(0) pins load issue). Bias via LDS. 1 wg/CU.
// W-stream ledger: wp1 advances 16x (prologue + HSTEP 0..14); wp2 16x
// (phase-1 HSTEP(15) seeds W2k0, phase-2 HSTEP 0..14).
__global__ __launch_bounds__(512, 2)
void fused_mlp(const float* __restrict__ X,
               const unsigned short* __restrict__ PK1,
               const float* __restrict__ B1,
               const unsigned short* __restrict__ PK2,
               const float* __restrict__ B2,
               float* __restrict__ Out)
{
    __shared__ __align__(16) unsigned char XH[131072];  // [128 rows][1024B], SWZ8; x then h
    __shared__ __align__(16) float BS[1024];            // bias: [0..511]=b1, [512..1023]=b2

    const int bid = blockIdx.x;
    const int nb = bid & 7;       // XCD-pin heuristic
    const int mt = bid >> 3;      // 0..63

    const int t = threadIdx.x;
    const int lane = t & 63;
    const int wid = t >> 6;       // 0..7 -> col slice wid*64
    const int l15 = lane & 15;
    const int lhi = lane >> 4;

    const int row0 = mt * 128;
    const int wc0  = nb * 512;

    // A-read bases: r = m*16+l15 (m 0..7). SWZ8(r) depends only on l15&7.
    // addr(m,p,kk) = ab[m>>2][kk&1] + (m&3)*16384 + (kk>>1)*128  (imm <= 50048)
    int ab[2][2];
    #pragma unroll
    for (int p = 0; p < 2; p++) {
        ab[0][p] = l15 * 1024 + ((p * 64 + lhi * 16) ^ SWZ8(l15));
        ab[1][p] = ab[0][p] + 65536;
    }

    const unsigned short* wp1 = PK1 + (size_t)(nb * 8 + wid) * 32768 + lane * 8;
    const unsigned short* wp2 = PK2 + (size_t)(nb * 8 + wid) * 32768 + lane * 8;

    f32x4 acc[8][4];
    #pragma unroll
    for (int m = 0; m < 8; m++)
        #pragma unroll
        for (int n = 0; n < 4; n++)
            acc[m][n] = (f32x4)(0.f);

    bf16x8 q0[4], q1[4];

#define LOADQ(Q, WPTR) { \
    _Pragma("unroll") for (int n = 0; n < 4; n++) \
        Q[n] = *(const bf16x8*)((WPTR) + n * 512); \
    (WPTR) += 2048; \
    __builtin_amdgcn_sched_barrier(0); }

// halfstep K: issue W loads for K+1 into QN, then 8x{af ds_read + 4 MFMA} on QC
#define HSTEP(K, QC, QN, WPTR) { \
    LOADQ(QN, WPTR); \
    __builtin_amdgcn_s_setprio(1); \
    _Pragma("unroll") for (int m = 0; m < 8; m++) { \
        bf16x8 af = *(const bf16x8*)(XH + ab[m >> 2][(K) & 1] + (m & 3) * 16384 + ((K) >> 1) * 128); \
        _Pragma("unroll") for (int n = 0; n < 4; n++) \
            acc[m][n] = __builtin_amdgcn_mfma_f32_16x16x32_bf16(af, QC[n], acc[m][n], 0, 0, 0); \
    } \
    __builtin_amdgcn_s_setprio(0); }

#define HSTEP_NL(K, QC) { \
    __builtin_amdgcn_s_setprio(1); \
    _Pragma("unroll") for (int m = 0; m < 8; m++) { \
        bf16x8 af = *(const bf16x8*)(XH + ab[m >> 2][(K) & 1] + (m & 3) * 16384 + ((K) >> 1) * 128); \
        _Pragma("unroll") for (int n = 0; n < 4; n++) \
            acc[m][n] = __builtin_amdgcn_mfma_f32_16x16x32_bf16(af, QC[n], acc[m][n], 0, 0, 0); \
    } \
    __builtin_amdgcn_s_setprio(0); }

#define BAR() { \
    asm volatile("s_waitcnt lgkmcnt(0)" ::: "memory"); \
    __builtin_amdgcn_s_barrier(); \
    __builtin_amdgcn_sched_barrier(0); }

    // ---- prologue: W1 kidx0 prefetch + bias->LDS + full x tile -> XH ----
    LOADQ(q0, wp1);
    BS[t]       = B1[wc0 + t];
    BS[512 + t] = B2[wc0 + t];
    {
        // 512 threads stage [128 rows][512 f32] -> bf16, SWZ8-swizzled
        const int sr = t >> 2;                        // row 0..127
        const int cb = (t & 3) * 256;                 // bf16-byte base within 1024B row
        const float* xr = X + (size_t)(row0 + sr) * DIM + wc0 + (t & 3) * 128;
        #pragma unroll
        for (int i = 0; i < 16; i++) {
            f32x4 a = *(const f32x4*)(xr + i * 8);
            f32x4 b = *(const f32x4*)(xr + i * 8 + 4);
            bf16x8 v;
            ((unsigned long long*)&v)[0] = pack4(a);
            ((unsigned long long*)&v)[1] = pack4(b);
            *(bf16x8*)(XH + sr * 1024 + ((cb + i * 16) ^ SWZ8(sr))) = v;
        }
    }
    BAR();

    // ================= phase 1: acc = x @ W1^T (barrier-free) =================
    HSTEP(0,  q0, q1, wp1)  HSTEP(1,  q1, q0, wp1)  HSTEP(2,  q0, q1, wp1)  HSTEP(3,  q1, q0, wp1)
    HSTEP(4,  q0, q1, wp1)  HSTEP(5,  q1, q0, wp1)  HSTEP(6,  q0, q1, wp1)  HSTEP(7,  q1, q0, wp1)
    HSTEP(8,  q0, q1, wp1)  HSTEP(9,  q1, q0, wp1)  HSTEP(10, q0, q1, wp1)  HSTEP(11, q1, q0, wp1)
    HSTEP(12, q0, q1, wp1)  HSTEP(13, q1, q0, wp1)  HSTEP(14, q0, q1, wp1)  HSTEP(15, q1, q0, wp2)

    BAR();   // all XH(x) ds_reads retired in every wave -> safe to overwrite with h

    // ---- h = relu(acc + b1) -> XH (same SWZ8 layout); bias from LDS ----
    #pragma unroll
    for (int n = 0; n < 4; n++) {
        const int c = wid * 64 + n * 16 + l15;
        const float bv = BS[c];
        #pragma unroll
        for (int m = 0; m < 8; m++) {
            #pragma unroll
            for (int rr = 0; rr < 4; rr++) {
                float v = acc[m][n][rr] + bv;
                v = v > 0.f ? v : 0.f;
                const int r = m * 16 + lhi * 4 + rr;
                *(unsigned short*)(XH + r * 1024 + ((c * 2) ^ SWZ8(r))) = f2bf(v);
            }
        }
    }
    BAR();   // h visible to all waves

    #pragma unroll
    for (int m = 0; m < 8; m++)
        #pragma unroll
        for (int n = 0; n < 4; n++)
            acc[m][n] = (f32x4)(0.f);

    // ================= phase 2: acc = h @ W2^T (barrier-free) =================
    HSTEP(0,  q0, q1, wp2)  HSTEP(1,  q1, q0, wp2)  HSTEP(2,  q0, q1, wp2)  HSTEP(3,  q1, q0, wp2)
    HSTEP(4,  q0, q1, wp2)  HSTEP(5,  q1, q0, wp2)  HSTEP(6,  q0, q1, wp2)  HSTEP(7,  q1, q0, wp2)
    HSTEP(8,  q0, q1, wp2)  HSTEP(9,  q1, q0, wp2)  HSTEP(10, q0, q1, wp2)  HSTEP(11, q1, q0, wp2)
    HSTEP(12, q0, q1, wp2)  HSTEP(13, q1, q0, wp2)  HSTEP(14, q0, q1, wp2)  HSTEP_NL(15, q1)

    // ---- epilogue: out = relu(acc + b2), f32; bias from LDS ----
    #pragma unroll
    for (int n = 0; n < 4; n++) {
        const int cl = wid * 64 + n * 16 + l15;
        const float bv = BS[512 + cl];
        const int c = wc0 + cl;
        #pragma unroll
        for (int m = 0; m < 8; m++) {
            const int rb = row0 + m * 16 + lhi * 4;
            #pragma unroll
            for (int rr = 0; rr < 4; rr++) {
                float v = acc[m][n][rr] + bv;
                Out[(size_t)(rb + rr) * DIM + c] = v > 0.f ? v : 0.f;
            }
        }
    }

#undef LOADQ
#undef HSTEP
#undef HSTEP_NL
#undef BAR
}

extern "C" void kernel_launch(void* const* d_in, const int* in_sizes, int n_in,
                              void* d_out, int out_size, void* d_ws, size_t ws_size,
                              hipStream_t stream) {
    const float* x  = (const float*)d_in[0];
    const float* W1 = (const float*)d_in[1];
    const float* b1 = (const float*)d_in[2];
    const float* W2 = (const float*)d_in[3];
    const float* b2 = (const float*)d_in[4];
    float* out = (float*)d_out;

    char* ws = (char*)d_ws;
    unsigned short* PK1 = (unsigned short*)ws;                 // 4 MB
    unsigned short* PK2 = (unsigned short*)(ws + (4u << 20));  // 4 MB

    pack_w<<<1024, 256, 0, stream>>>(W1, PK1);
    pack_w<<<1024, 256, 0, stream>>>(W2, PK2);

    const int GRID = NB * (BATCH / 128);    // 512
    fused_mlp<<<GRID, 512, 0, stream>>>(x, PK1, b1, PK2, b2, out);
}